// Round 7
// baseline (721.160 us; speedup 1.0000x reference)
//
#include <hip/hip_runtime.h>
#include <cstdint>
#include <cstddef>

typedef unsigned short u16;
typedef __attribute__((ext_vector_type(8))) short short8;
typedef __attribute__((ext_vector_type(4))) float floatx4;
typedef __attribute__((ext_vector_type(4))) unsigned short ushort4v;

constexpr int D_ = 1024;
constexpr int B_ = 8;
constexpr int L_ = 4096;
constexpr int M_ = B_ * L_;        // 32768 tokens
constexpr int NCHUNK = 64;
constexpr int CLEN = L_ / NCHUNK;  // 64
constexpr float EPS_ = 1e-6f;
constexpr size_t WIN_ELEMS = (size_t)3 * D_ * D_;   // 3145728
constexpr size_t WOUT_ELEMS = (size_t)D_ * D_;      // 1048576
constexpr int PREPW_BLOCKS = (int)((WIN_ELEMS + WOUT_ELEMS) / 8 / 256);  // 2048

__device__ __forceinline__ float bf2f(u16 b) {
    union { unsigned u; float f; } x; x.u = ((unsigned)b) << 16; return x.f;
}
__device__ __forceinline__ u16 f2bf(float f) {
    union { float f; unsigned u; } x; x.f = f;
    unsigned r = x.u + 0x7fffu + ((x.u >> 16) & 1u);
    return (u16)(r >> 16);
}
__device__ __forceinline__ float sigmoidf_(float x) {
    return 1.f / (1.f + __expf(-x));
}
__device__ __forceinline__ short8 cvt8(const float* __restrict__ p) {
    float4 a = *(const float4*)p;
    float4 b = *(const float4*)(p + 4);
    short8 o;
    o[0] = (short)f2bf(a.x); o[1] = (short)f2bf(a.y);
    o[2] = (short)f2bf(a.z); o[3] = (short)f2bf(a.w);
    o[4] = (short)f2bf(b.x); o[5] = (short)f2bf(b.y);
    o[6] = (short)f2bf(b.z); o[7] = (short)f2bf(b.w);
    return o;
}
// async 16B/lane global->LDS; LDS dest = wave-uniform base + lane*16
__device__ __forceinline__ void gload16(const void* g, void* l) {
    __builtin_amdgcn_global_load_lds((const __attribute__((address_space(1))) void*)g,
                                     (__attribute__((address_space(3))) void*)l, 16, 0, 0);
}

// ---------- prep: fused RMSNorm rows (blocks 0..M_-1) + weight bf16 cast (rest) ----------
__global__ __launch_bounds__(256) void prep_kernel(const float* __restrict__ x,
                                                   const float* __restrict__ scale,
                                                   u16* __restrict__ xn,
                                                   const float* __restrict__ w_in,
                                                   const float* __restrict__ w_out,
                                                   u16* __restrict__ w_in_bf,
                                                   u16* __restrict__ w_out_bf) {
    const int t = threadIdx.x;
    if ((int)blockIdx.x >= M_) {
        size_t i8 = ((size_t)(blockIdx.x - M_) * 256 + t) * 8;
        if (i8 < WIN_ELEMS) {
            *(short8*)(w_in_bf + i8) = cvt8(w_in + i8);
        } else {
            size_t j = i8 - WIN_ELEMS;
            *(short8*)(w_out_bf + j) = cvt8(w_out + j);
        }
        return;
    }
    const int row = blockIdx.x;
    const float* xr = x + (size_t)row * D_;
    float4 xv = ((const float4*)xr)[t];
    float ss = xv.x * xv.x + xv.y * xv.y + xv.z * xv.z + xv.w * xv.w;
#pragma unroll
    for (int m = 32; m >= 1; m >>= 1) ss += __shfl_xor(ss, m, 64);
    __shared__ float red[4];
    const int wave = t >> 6, lane = t & 63;
    if (lane == 0) red[wave] = ss;
    __syncthreads();
    float tot = red[0] + red[1] + red[2] + red[3];
    float inv = 1.f / (sqrtf(tot * (1.f / D_)) + EPS_);
    float4 sv = ((const float4*)scale)[t];
    ushort4v o;
    o[0] = f2bf(xv.x * inv * sv.x);
    o[1] = f2bf(xv.y * inv * sv.y);
    o[2] = f2bf(xv.z * inv * sv.z);
    o[3] = f2bf(xv.w * inv * sv.w);
    ((ushort4v*)(xn + (size_t)row * D_))[t] = o;
}

// ============================================================================
// 256x256 bf16 GEMM core — quad-buffered BK=32 with full intra-wave pipelining.
//   8 waves (512 thr) = 2(M) x 4(N); per-wave out 128x64; 32 K-tiles of 32.
//   LDS: 4 buffers x (A[256][32] 16KB + B[256][32] 16KB) = 128 KiB.
//   64B rows are naturally bank-conflict-free for the b128 fragment pattern
//   (8 lanes per bank-quad) -> NO swizzle, linear global_load_lds staging.
//   Per tile t (one barrier each):
//     prefetch 12 ds_read_b128 of frags(t+1) from buf[(t+1)%4]  (no consumer now)
//     stage buf[(t+3)%4] via 4 global_load_lds                   (lookahead 3)
//     32 independent MFMAs on frags(t) already in registers      (zero lgkm wait)
//     s_waitcnt vmcnt(4)  -> buf[t+2] landed  ;  s_barrier
//   Hazards (counted): stage buf[t+3]==buf[t-1] last read at t-2, retired by lgkm
//   before barrier(t-1); prefetch reads buf[t+1] staged at t-2, drained by
//   vmcnt(4)@t-1 + barrier. MFMA and LDS pipes now overlap within each wave.
// ============================================================================

#define BARRIER_() do { __builtin_amdgcn_sched_barrier(0); \
    __builtin_amdgcn_s_barrier(); \
    __builtin_amdgcn_sched_barrier(0); } while (0)
#define VM4_() asm volatile("s_waitcnt vmcnt(4)" ::: "memory")
#define VM0_() asm volatile("s_waitcnt vmcnt(0)" ::: "memory")

// read the 12 fragments of one tile from buffer bsel (compile-time 0..3)
#define RD_(S, bsel) do { \
    const char* aP_ = ((bsel) < 2 ? aLo : aHi) + ((bsel) & 1) * 32768; \
    const char* bP_ = ((bsel) < 2 ? bLo : bHi) + ((bsel) & 1) * 32768; \
    _Pragma("unroll") for (int m_ = 0; m_ < 8; ++m_) \
        S##a[m_] = *(const short8*)(aP_ + m_ * 1024); \
    _Pragma("unroll") for (int n_ = 0; n_ < 4; ++n_) \
        S##b[n_] = *(const short8*)(bP_ + n_ * 1024); \
} while (0)

// stage one 32-wide K-slice into buffer bsel; srcs in u16 elems
#define STAGE_(bsel, pa, pb, koff) do { \
    u16* lA_ = SH + (bsel) * 16384 + wid * 512; \
    gload16((pa) + (koff), lA_);            gload16((pa) + (koff) + 131072, lA_ + 4096); \
    gload16((pb) + (koff), lA_ + 8192);     gload16((pb) + (koff) + 131072, lA_ + 12288); \
} while (0)

#define MFMA_(S) do { __builtin_amdgcn_s_setprio(1); \
    _Pragma("unroll") for (int m_ = 0; m_ < 8; ++m_) \
    _Pragma("unroll") for (int n_ = 0; n_ < 4; ++n_) \
        acc[m_][n_] = __builtin_amdgcn_mfma_f32_16x16x32_bf16( \
            S##a[m_], S##b[n_], acc[m_][n_], 0, 0, 0); \
    __builtin_amdgcn_s_setprio(0); } while (0)

__device__ __forceinline__ void gemm256_core(const u16* __restrict__ gA,
                                             const u16* __restrict__ gB,
                                             int m0, int n0,
                                             u16* __restrict__ SH,
                                             floatx4 (&acc)[8][4]) {
    const int t = threadIdx.x;
    const int wid = t >> 6, lane = t & 63;
    const int wr = wid >> 2, wc = wid & 3;
    const int l15 = lane & 15, quad = lane >> 4;

    // staging sources: thread t loads A row m0 + t/4, elems (t&3)*8 (+row 128 for 2nd)
    const u16* gA0 = gA + (size_t)(m0 + (t >> 2)) * 1024 + (t & 3) * 8;
    const u16* gB0 = gB + (size_t)(n0 + (t >> 2)) * 1024 + (t & 3) * 8;
    // fragment-read bases (bytes): A row wr*128+l15, k-chunk quad*16B; buffers 2,3 via +64K
    char* aLo = (char*)SH + (wr * 128 + l15) * 64 + quad * 16;
    char* aHi = aLo + 65536;
    char* bLo = (char*)SH + 16384 + (wc * 64 + l15) * 64 + quad * 16;
    char* bHi = bLo + 65536;

    short8 s0a[8], s0b[4], s1a[8], s1b[4];
#pragma unroll
    for (int i = 0; i < 8; i++)
#pragma unroll
        for (int j = 0; j < 4; j++) { floatx4 z = {0.f, 0.f, 0.f, 0.f}; acc[i][j] = z; }

    // prologue: stage tiles 0,1,2; wait bufs 0,1 landed (vmcnt(4) leaves buf2 in flight)
    STAGE_(0, gA0, gB0, 0);
    STAGE_(1, gA0, gB0, 32);
    STAGE_(2, gA0, gB0, 64);
    VM4_();
    BARRIER_();
    RD_(s0, 0);                       // frags of tile 0

    const u16* gAs = gA0 + 96;        // rolling stage src: k elems of tile (4*it+3)
    const u16* gBs = gB0 + 96;
#pragma unroll 1
    for (int it = 0; it < 7; ++it) {  // tiles 0..27
        RD_(s1, 1); STAGE_(3, gAs, gBs, 0);  MFMA_(s0); VM4_(); BARRIER_();
        RD_(s0, 2); STAGE_(0, gAs, gBs, 32); MFMA_(s1); VM4_(); BARRIER_();
        RD_(s1, 3); STAGE_(1, gAs, gBs, 64); MFMA_(s0); VM4_(); BARRIER_();
        RD_(s0, 0); STAGE_(2, gAs, gBs, 96); MFMA_(s1); VM4_(); BARRIER_();
        gAs += 128; gBs += 128;
    }
    // peel tiles 28..31 (gAs = gA0 + 992 = k-elems of tile 31)
    RD_(s1, 1); STAGE_(3, gAs, gBs, 0); MFMA_(s0); VM4_(); BARRIER_();  // t=28
    RD_(s0, 2);                         MFMA_(s1); VM0_(); BARRIER_();  // t=29
    RD_(s1, 3);                         MFMA_(s0);                      // t=30
    MFMA_(s1);                                                          // t=31
    BARRIER_();                        // all frag reads retired before epilogue reuses SH
}

// GEMM1: xn @ w_in^T, fused activations; C staged via LDS for full-line stores.
// Grid dim3(12, 128), n-fastest: all 12 column-blocks of an A-panel run
// contemporaneously -> A stays L2/L3-hot (round-1/4-verified ordering).
__global__ __launch_bounds__(512, 2) void gemm1_kernel(const u16* __restrict__ xn,
                                                       const u16* __restrict__ w_in,
                                                       u16* __restrict__ g_buf,
                                                       u16* __restrict__ v_buf,
                                                       u16* __restrict__ f_buf) {
    __shared__ __align__(16) u16 SH[65536];   // 128 KiB: 4 K-buffers, then C-tile
    const int m0 = blockIdx.y * 256;
    const int n0 = blockIdx.x * 256;
    floatx4 acc[8][4];
    gemm256_core(xn, w_in, m0, n0, SH, acc);

    const int t = threadIdx.x;
    const int wid = t >> 6, lane = t & 63;
    const int wr = wid >> 2, wc = wid & 3;
    const int l15 = lane & 15, quad = lane >> 4;
    const int plane = n0 >> 10;                    // tile fully inside one plane
    const int cbase = n0 & 1023;
    u16* dst = (plane == 0) ? g_buf : ((plane == 1) ? v_buf : f_buf);

    // acc -> LDS [256][256] bf16, 8B-chunk XOR swizzle per row
#pragma unroll
    for (int mt = 0; mt < 8; mt++) {
#pragma unroll
        for (int r = 0; r < 4; r++) {
            int row = wr * 128 + mt * 16 + quad * 4 + r;
            int xr = (row & 7) << 3;
#pragma unroll
            for (int nt = 0; nt < 4; nt++) {
                int colb = (wc * 64 + nt * 16 + l15) * 2;
                float val = acc[mt][nt][r];
                if (plane == 0) val = sigmoidf_(val);
                else if (plane == 2) val = sigmoidf_(val - 1.f);
                *(u16*)((char*)SH + row * 512 + (colb ^ xr)) = f2bf(val);
            }
        }
    }
    __syncthreads();
    // read back rows linearly; 64 lanes x 8B = 512 B contiguous per store instr
    const int lane8 = lane * 8;
#pragma unroll 4
    for (int i = 0; i < 32; i++) {
        int row = wid + i * 8;
        int xr = (row & 7) << 3;
        uint2 v = *(const uint2*)((const char*)SH + row * 512 + (lane8 ^ xr));
        *(uint2*)(dst + (size_t)(m0 + row) * 1024 + cbase + lane * 4) = v;
    }
}

// GEMM2: out_pre(bf16) @ w_out_bf^T + residual x(fp32) -> out fp32
__global__ __launch_bounds__(512, 2) void gemm2_kernel(const u16* __restrict__ op,
                                                       const u16* __restrict__ w_out,
                                                       const float* __restrict__ xres,
                                                       float* __restrict__ out) {
    __shared__ __align__(16) u16 SH[65536];
    const int m0 = blockIdx.y * 256;
    const int n0 = blockIdx.x * 256;
    floatx4 acc[8][4];
    gemm256_core(op, w_out, m0, n0, SH, acc);

    const int t = threadIdx.x;
    const int wid = t >> 6, lane = t & 63;
    const int wr = wid >> 2, wc = wid & 3;
    const int l15 = lane & 15, quad = lane >> 4;
    const int ncol0 = n0 + wc * 64;
    const int mrow0 = m0 + wr * 128 + quad * 4;
#pragma unroll
    for (int mt = 0; mt < 8; mt++) {
#pragma unroll
        for (int r = 0; r < 4; r++) {
            int m = mrow0 + mt * 16 + r;
#pragma unroll
            for (int nt = 0; nt < 4; nt++) {
                size_t idx = (size_t)m * 1024 + ncol0 + nt * 16 + l15;
                out[idx] = acc[mt][nt][r] + xres[idx];
            }
        }
    }
}

// ---------------- Chunked parallel scan over L (3 passes) ----------------
__global__ __launch_bounds__(256) void scan1_kernel(const u16* __restrict__ f_buf,
                                                    const u16* __restrict__ v_buf,
                                                    float* __restrict__ Aarr,
                                                    float* __restrict__ Barr) {
    const int wid = blockIdx.x * 4 + (threadIdx.x >> 6);  // 0..8191
    const int lane = threadIdx.x & 63;
    const int b = wid >> 10;
    const int rem = wid & 1023;
    const int c = rem >> 4;
    const int db = (rem & 15) * 64 + lane;
    float A = 1.f, Bv = 0.f;
    size_t base = ((size_t)b * L_ + c * CLEN) * D_ + db;
#pragma unroll 4
    for (int tt = 0; tt < CLEN; tt++) {
        float fv = bf2f(f_buf[base + (size_t)tt * D_]);
        float vv = bf2f(v_buf[base + (size_t)tt * D_]);
        A *= fv;
        Bv = fv * Bv + (1.f - fv) * vv;
    }
    size_t sidx = ((size_t)b * NCHUNK + c) * D_ + db;
    Aarr[sidx] = A;
    Barr[sidx] = Bv;
}

__global__ __launch_bounds__(256) void scan2_kernel(const float* __restrict__ Aarr,
                                                    const float* __restrict__ Barr,
                                                    float* __restrict__ hin) {
    const int id = blockIdx.x * 256 + threadIdx.x;  // 0..8191
    const int b = id >> 10, d = id & 1023;
    float h = 0.f;
    for (int c = 0; c < NCHUNK; c++) {
        size_t idx = ((size_t)b * NCHUNK + c) * D_ + d;
        hin[idx] = h;
        h = Aarr[idx] * h + Barr[idx];
    }
}

__global__ __launch_bounds__(256) void scan3_kernel(const u16* __restrict__ f_buf,
                                                    const u16* __restrict__ v_buf,
                                                    u16* g_io,
                                                    const float* __restrict__ hin) {
    const int wid = blockIdx.x * 4 + (threadIdx.x >> 6);
    const int lane = threadIdx.x & 63;
    const int b = wid >> 10;
    const int rem = wid & 1023;
    const int c = rem >> 4;
    const int db = (rem & 15) * 64 + lane;
    size_t base = ((size_t)b * L_ + c * CLEN) * D_ + db;
    float h = hin[((size_t)b * NCHUNK + c) * D_ + db];
#pragma unroll 4
    for (int tt = 0; tt < CLEN; tt++) {
        size_t idx = base + (size_t)tt * D_;
        float fv = bf2f(f_buf[idx]);
        float vv = bf2f(v_buf[idx]);
        float gv = bf2f(g_io[idx]);
        h = fv * h + (1.f - fv) * vv;
        g_io[idx] = f2bf(gv * h);
    }
}

extern "C" void kernel_launch(void* const* d_in, const int* in_sizes, int n_in,
                              void* d_out, int out_size, void* d_ws, size_t ws_size,
                              hipStream_t stream) {
    const float* x     = (const float*)d_in[0];  // [8,4096,1024] fp32
    const float* w_in  = (const float*)d_in[1];  // [3072,1024]  fp32
    const float* w_out = (const float*)d_in[2];  // [1024,1024]  fp32
    const float* scale = (const float*)d_in[3];  // [1024]       fp32
    float* out = (float*)d_out;                  // [8,4096,1024] fp32 (128 MiB)

    // d_out doubles as scratch before the final GEMM: f and v bf16 planes.
    u16* f_buf = (u16*)d_out;                        // 64 MiB
    u16* v_buf = (u16*)d_out + (size_t)M_ * D_;      // 64 MiB

    // Workspace (~142 MiB): xn(64) + g(64) + w_in_bf(6) + w_out_bf(2) + scan(6)
    char* ws = (char*)d_ws;
    const size_t PLANE = (size_t)M_ * D_ * sizeof(u16);  // 64 MiB
    u16* xn    = (u16*)ws;
    u16* g_buf = (u16*)(ws + PLANE);
    u16* w_in_bf  = (u16*)(ws + 2 * PLANE);
    u16* w_out_bf = w_in_bf + WIN_ELEMS;
    float* Aarr = (float*)(ws + 2 * PLANE + (WIN_ELEMS + WOUT_ELEMS) * sizeof(u16));
    float* Barr = Aarr + (size_t)B_ * NCHUNK * D_;
    float* hin  = Barr + (size_t)B_ * NCHUNK * D_;

    prep_kernel<<<M_ + PREPW_BLOCKS, 256, 0, stream>>>(x, scale, xn, w_in, w_out,
                                                       w_in_bf, w_out_bf);
    gemm1_kernel<<<dim3(3 * D_ / 256, M_ / 256), 512, 0, stream>>>(
        xn, w_in_bf, g_buf, v_buf, f_buf);
    scan1_kernel<<<(B_ * NCHUNK * 16) / 4, 256, 0, stream>>>(f_buf, v_buf, Aarr, Barr);
    scan2_kernel<<<(B_ * D_) / 256, 256, 0, stream>>>(Aarr, Barr, hin);
    scan3_kernel<<<(B_ * NCHUNK * 16) / 4, 256, 0, stream>>>(f_buf, v_buf, g_buf, hin);
    gemm2_kernel<<<dim3(D_ / 256, M_ / 256), 512, 0, stream>>>(g_buf, w_out_bf, x, out);
}

// Round 8
// 614.929 us; speedup vs baseline: 1.1728x; 1.1728x over previous
//
#include <hip/hip_runtime.h>
#include <cstdint>
#include <cstddef>

typedef unsigned short u16;
typedef __attribute__((ext_vector_type(8))) short short8;
typedef __attribute__((ext_vector_type(4))) float floatx4;
typedef __attribute__((ext_vector_type(4))) unsigned short ushort4v;

constexpr int D_ = 1024;
constexpr int B_ = 8;
constexpr int L_ = 4096;
constexpr int M_ = B_ * L_;        // 32768 tokens
constexpr int NCHUNK = 64;
constexpr int CLEN = L_ / NCHUNK;  // 64
constexpr float EPS_ = 1e-6f;
constexpr size_t WIN_ELEMS = (size_t)3 * D_ * D_;   // 3145728
constexpr size_t WOUT_ELEMS = (size_t)D_ * D_;      // 1048576
constexpr int NT_K = 16;           // K=1024 / BK=64
constexpr int PREPW_BLOCKS = (int)((WIN_ELEMS + WOUT_ELEMS) / 8 / 256);  // 2048

__device__ __forceinline__ float bf2f(u16 b) {
    union { unsigned u; float f; } x; x.u = ((unsigned)b) << 16; return x.f;
}
__device__ __forceinline__ u16 f2bf(float f) {
    union { float f; unsigned u; } x; x.f = f;
    unsigned r = x.u + 0x7fffu + ((x.u >> 16) & 1u);
    return (u16)(r >> 16);
}
__device__ __forceinline__ float sigmoidf_(float x) {
    return 1.f / (1.f + __expf(-x));
}
__device__ __forceinline__ short8 cvt8(const float* __restrict__ p) {
    float4 a = *(const float4*)p;
    float4 b = *(const float4*)(p + 4);
    short8 o;
    o[0] = (short)f2bf(a.x); o[1] = (short)f2bf(a.y);
    o[2] = (short)f2bf(a.z); o[3] = (short)f2bf(a.w);
    o[4] = (short)f2bf(b.x); o[5] = (short)f2bf(b.y);
    o[6] = (short)f2bf(b.z); o[7] = (short)f2bf(b.w);
    return o;
}
// async 16B/lane global->LDS; LDS dest = wave-uniform base + lane*16
__device__ __forceinline__ void gload16(const void* g, void* l) {
    __builtin_amdgcn_global_load_lds((const __attribute__((address_space(1))) void*)g,
                                     (__attribute__((address_space(3))) void*)l, 16, 0, 0);
}

// ---------- prep: fused RMSNorm rows (blocks 0..M_-1) + weight bf16 cast (rest) ----------
__global__ __launch_bounds__(256) void prep_kernel(const float* __restrict__ x,
                                                   const float* __restrict__ scale,
                                                   u16* __restrict__ xn,
                                                   const float* __restrict__ w_in,
                                                   const float* __restrict__ w_out,
                                                   u16* __restrict__ w_in_bf,
                                                   u16* __restrict__ w_out_bf) {
    const int t = threadIdx.x;
    if ((int)blockIdx.x >= M_) {
        size_t i8 = ((size_t)(blockIdx.x - M_) * 256 + t) * 8;
        if (i8 < WIN_ELEMS) {
            *(short8*)(w_in_bf + i8) = cvt8(w_in + i8);
        } else {
            size_t j = i8 - WIN_ELEMS;
            *(short8*)(w_out_bf + j) = cvt8(w_out + j);
        }
        return;
    }
    const int row = blockIdx.x;
    const float* xr = x + (size_t)row * D_;
    float4 xv = ((const float4*)xr)[t];
    float ss = xv.x * xv.x + xv.y * xv.y + xv.z * xv.z + xv.w * xv.w;
#pragma unroll
    for (int m = 32; m >= 1; m >>= 1) ss += __shfl_xor(ss, m, 64);
    __shared__ float red[4];
    const int wave = t >> 6, lane = t & 63;
    if (lane == 0) red[wave] = ss;
    __syncthreads();
    float tot = red[0] + red[1] + red[2] + red[3];
    float inv = 1.f / (sqrtf(tot * (1.f / D_)) + EPS_);
    float4 sv = ((const float4*)scale)[t];
    ushort4v o;
    o[0] = f2bf(xv.x * inv * sv.x);
    o[1] = f2bf(xv.y * inv * sv.y);
    o[2] = f2bf(xv.z * inv * sv.z);
    o[3] = f2bf(xv.w * inv * sv.w);
    ((ushort4v*)(xn + (size_t)row * D_))[t] = o;
}

// ============================================================================
// 256x256 bf16 GEMM core — round-6 base, 2 merged regions per K-tile.
//   8 waves (512 thr) = 2(M) x 4(N); per-wave out 128x64; BK=64; 2 K-tiles/iter.
//   LDS: A[2][256][64] + B[2][256][64] bf16 = 128 KiB, double-buffered,
//   row stride 128 B with XOR swizzle (byte ^= ((row&7)<<4)); global source
//   pre-swizzled for linear global_load_lds (rule 21).
//   Per tile, TWO regions (2 barriers, was 4):
//     R1: 16 ds_read (A-low 8, B-even 4, B-odd 4) | stage H1,H3(t+1)->other
//         | 32 MFMA (A-low x B-all)
//     R2:  8 ds_read (A-high)                     | stage H0,H2(t+2)->current
//         | 32 MFMA (A-high x B-all; bfv persists) | vmcnt(4)
//   B-odd/A-high reads issue before the first MFMA cluster of their region and
//   complete under it. Hazards: stage targets' readers drained >=1 barrier
//   earlier (H1/H3: region2(t-1); H0/H2: region1(t)); 4 gloads/region ->
//   vmcnt(4) at tile end leaves exactly R2(t)'s loads in flight, guaranteeing
//   tile t+1 fully landed. Each fragment read from LDS exactly once per tile.
// ============================================================================

#define STAGE_A_(buf, half, koff) do { \
    const u16* g_ = gA0 + (koff) + (half) * 65536; \
    u16* l_ = (buf) + ((half) * 64 + iw) * 64; \
    gload16(g_, l_); gload16(g_ + 131072, l_ + 8192); } while (0)
#define STAGE_B_(buf, half, koff) do { \
    const u16* g_ = gB0 + (koff) + (half) * 32768; \
    u16* l_ = (buf) + (rBw + (half) * 32) * 64; \
    gload16(g_, l_); gload16(g_ + 131072, l_ + 8192); } while (0)
#define BARRIER_() do { __builtin_amdgcn_sched_barrier(0); \
    __builtin_amdgcn_s_barrier(); \
    __builtin_amdgcn_sched_barrier(0); } while (0)
#define LDA4_(mlo) do { \
    _Pragma("unroll") for (int m_ = 0; m_ < 4; ++m_) { \
      int o_ = aOff + ((mlo) + m_) * 2048; \
      af[m_][0] = *(const short8*)((const char*)curA + o_); \
      af[m_][1] = *(const short8*)((const char*)curA + (o_ ^ 64)); } } while (0)
#define LDB2_(nlo) do { \
    _Pragma("unroll") for (int n_ = 0; n_ < 2; ++n_) { \
      int o_ = bOff + ((nlo) + n_) * 2048; \
      bfv[(nlo) + n_][0] = *(const short8*)((const char*)curB + o_); \
      bfv[(nlo) + n_][1] = *(const short8*)((const char*)curB + (o_ ^ 64)); } } while (0)
#define MFMA_Q_(mlo, nlo) do { \
    __builtin_amdgcn_s_setprio(1); \
    _Pragma("unroll") for (int m_ = 0; m_ < 4; ++m_) \
    _Pragma("unroll") for (int n_ = 0; n_ < 2; ++n_) \
    _Pragma("unroll") for (int k_ = 0; k_ < 2; ++k_) \
      acc[(mlo) + m_][(nlo) + n_] = __builtin_amdgcn_mfma_f32_16x16x32_bf16( \
          af[m_][k_], bfv[(nlo) + n_][k_], acc[(mlo) + m_][(nlo) + n_], 0, 0, 0); \
    __builtin_amdgcn_s_setprio(0); } while (0)

__device__ __forceinline__ void tile_step(int tt, u16* curA, u16* curB, u16* othA, u16* othB,
                                          const u16* gA0, const u16* gB0, int iw, int rBw,
                                          int aOff, int bOff, floatx4 (&acc)[8][4]) {
    short8 af[4][2], bfv[4][2];
    const int k1 = (tt + 1) * 64, k2 = (tt + 2) * 64;
    const bool s1 = (tt + 1 < NT_K), s2 = (tt + 2 < NT_K);
    // R1: A-low + all B frags; stage H1,H3(t+1) -> other buffer
    LDA4_(0); LDB2_(0); LDB2_(2);
    if (s1) { STAGE_A_(othA, 1, k1); STAGE_B_(othB, 1, k1); }
    MFMA_Q_(0, 0);
    MFMA_Q_(0, 2);
    BARRIER_();
    // R2: A-high frags (bfv persists); stage H0,H2(t+2) -> CURRENT buffer
    LDA4_(4);
    if (s2) { STAGE_A_(curA, 0, k2); STAGE_B_(curB, 0, k2); }
    MFMA_Q_(4, 0);
    MFMA_Q_(4, 2);
    if (s2)      { asm volatile("s_waitcnt vmcnt(4)" ::: "memory"); }  // t+1 fully landed
    else if (s1) { asm volatile("s_waitcnt vmcnt(0)" ::: "memory"); }  // tail: drain
    BARRIER_();
}

__device__ __forceinline__ void gemm256_core(const u16* __restrict__ gA,
                                             const u16* __restrict__ gB,
                                             int m0, int n0,
                                             u16* __restrict__ As, u16* __restrict__ Bs,
                                             floatx4 (&acc)[8][4]) {
    const int t = threadIdx.x;
    const int wid = t >> 6, lane = t & 63;
    const int wr = wid >> 2, wc = wid & 3;
    const int l15 = lane & 15, quad = lane >> 4;
    const int jrow = lane >> 3, jc = lane & 7;
    const int swz = ((jc ^ (jrow & 7)) << 3);             // pre-swizzled source chunk (elems)
    const u16* gA0 = gA + (size_t)(m0 + wid * 8 + jrow) * 1024 + swz;
    const int i0 = wid * 8 + jrow;
    const int rB0 = ((i0 >> 5) << 6) + (i0 & 31);         // B even-block row mapping
    const u16* gB0 = gB + (size_t)(n0 + rB0) * 1024 + swz;
    const int iw = wid * 8;
    const int rBw = ((iw >> 5) << 6) + (iw & 31);
    const int c0 = (quad * 16) ^ ((l15 & 7) << 4);
    const int aOff = (wr * 128 + l15) * 128 + c0;
    const int bOff = (wc * 64 + l15) * 128 + c0;

#pragma unroll
    for (int i = 0; i < 8; i++)
#pragma unroll
        for (int j = 0; j < 4; j++) { floatx4 z = {0.f, 0.f, 0.f, 0.f}; acc[i][j] = z; }

    // prologue: tile0 all 4 halves + tile1's H0,H2 (12 loads; allow last 2 halves in flight)
    STAGE_A_(As, 0, 0); STAGE_A_(As, 1, 0);
    STAGE_B_(Bs, 0, 0); STAGE_B_(Bs, 1, 0);
    STAGE_A_(As + 16384, 0, 64);
    STAGE_B_(Bs + 16384, 0, 64);
    asm volatile("s_waitcnt vmcnt(4)" ::: "memory");
    BARRIER_();

#pragma unroll 1
    for (int tt = 0; tt < NT_K; tt += 2) {
        tile_step(tt,     As,         Bs,         As + 16384, Bs + 16384,
                  gA0, gB0, iw, rBw, aOff, bOff, acc);
        tile_step(tt + 1, As + 16384, Bs + 16384, As,         Bs,
                  gA0, gB0, iw, rBw, aOff, bOff, acc);
    }
}

// GEMM1: xn @ w_in^T, fused activations; C staged via LDS for full-line stores.
// Grid dim3(12, 128), n-fastest: all 12 column-blocks of an A-panel run
// contemporaneously -> A stays L2/L3-hot (round-1/4-verified ordering).
__global__ __launch_bounds__(512, 2) void gemm1_kernel(const u16* __restrict__ xn,
                                                       const u16* __restrict__ w_in,
                                                       u16* __restrict__ g_buf,
                                                       u16* __restrict__ v_buf,
                                                       u16* __restrict__ f_buf) {
    __shared__ __align__(16) u16 SH[65536];   // 128 KiB: A/B dbuf, then C-tile
    const int m0 = blockIdx.y * 256;
    const int n0 = blockIdx.x * 256;
    floatx4 acc[8][4];
    gemm256_core(xn, w_in, m0, n0, SH, SH + 32768, acc);

    const int t = threadIdx.x;
    const int wid = t >> 6, lane = t & 63;
    const int wr = wid >> 2, wc = wid & 3;
    const int l15 = lane & 15, quad = lane >> 4;
    const int plane = n0 >> 10;                    // tile fully inside one plane
    const int cbase = n0 & 1023;
    u16* dst = (plane == 0) ? g_buf : ((plane == 1) ? v_buf : f_buf);

    // acc -> LDS [256][256] bf16, 8B-chunk XOR swizzle per row
#pragma unroll
    for (int mt = 0; mt < 8; mt++) {
#pragma unroll
        for (int r = 0; r < 4; r++) {
            int row = wr * 128 + mt * 16 + quad * 4 + r;
            int xr = (row & 7) << 3;
#pragma unroll
            for (int nt = 0; nt < 4; nt++) {
                int colb = (wc * 64 + nt * 16 + l15) * 2;
                float val = acc[mt][nt][r];
                if (plane == 0) val = sigmoidf_(val);
                else if (plane == 2) val = sigmoidf_(val - 1.f);
                *(u16*)((char*)SH + row * 512 + (colb ^ xr)) = f2bf(val);
            }
        }
    }
    __syncthreads();
    // read back rows linearly; 64 lanes x 8B = 512 B contiguous per store instr
    const int lane8 = lane * 8;
#pragma unroll 4
    for (int i = 0; i < 32; i++) {
        int row = wid + i * 8;
        int xr = (row & 7) << 3;
        uint2 v = *(const uint2*)((const char*)SH + row * 512 + (lane8 ^ xr));
        *(uint2*)(dst + (size_t)(m0 + row) * 1024 + cbase + lane * 4) = v;
    }
}

// GEMM2: out_pre(bf16) @ w_out_bf^T + residual x(fp32) -> out fp32
__global__ __launch_bounds__(512, 2) void gemm2_kernel(const u16* __restrict__ op,
                                                       const u16* __restrict__ w_out,
                                                       const float* __restrict__ xres,
                                                       float* __restrict__ out) {
    __shared__ __align__(16) u16 SH[65536];
    const int m0 = blockIdx.y * 256;
    const int n0 = blockIdx.x * 256;
    floatx4 acc[8][4];
    gemm256_core(op, w_out, m0, n0, SH, SH + 32768, acc);

    const int t = threadIdx.x;
    const int wid = t >> 6, lane = t & 63;
    const int wr = wid >> 2, wc = wid & 3;
    const int l15 = lane & 15, quad = lane >> 4;
    const int ncol0 = n0 + wc * 64;
    const int mrow0 = m0 + wr * 128 + quad * 4;
#pragma unroll
    for (int mt = 0; mt < 8; mt++) {
#pragma unroll
        for (int r = 0; r < 4; r++) {
            int m = mrow0 + mt * 16 + r;
#pragma unroll
            for (int nt = 0; nt < 4; nt++) {
                size_t idx = (size_t)m * 1024 + ncol0 + nt * 16 + l15;
                out[idx] = acc[mt][nt][r] + xres[idx];
            }
        }
    }
}

// ---------------- Chunked parallel scan over L (3 passes, 4 dims/lane) ----------------
__global__ __launch_bounds__(256) void scan1_kernel(const u16* __restrict__ f_buf,
                                                    const u16* __restrict__ v_buf,
                                                    float* __restrict__ Aarr,
                                                    float* __restrict__ Barr) {
    const int wid = blockIdx.x * 4 + (threadIdx.x >> 6);  // 0..2047
    const int lane = threadIdx.x & 63;
    const int b = wid >> 8;
    const int rem = wid & 255;
    const int c = rem >> 2;
    const int d0 = (rem & 3) * 256 + lane * 4;
    float A[4], Bv[4];
#pragma unroll
    for (int j = 0; j < 4; j++) { A[j] = 1.f; Bv[j] = 0.f; }
    size_t base = ((size_t)b * L_ + c * CLEN) * D_ + d0;
#pragma unroll 2
    for (int tt = 0; tt < CLEN; tt++) {
        ushort4v f4 = *(const ushort4v*)(f_buf + base + (size_t)tt * D_);
        ushort4v v4 = *(const ushort4v*)(v_buf + base + (size_t)tt * D_);
#pragma unroll
        for (int j = 0; j < 4; j++) {
            float fv = bf2f(f4[j]);
            float vv = bf2f(v4[j]);
            A[j] *= fv;
            Bv[j] = fv * Bv[j] + (1.f - fv) * vv;
        }
    }
    size_t sidx = ((size_t)b * NCHUNK + c) * D_ + d0;
    floatx4 oA = {A[0], A[1], A[2], A[3]};
    floatx4 oB = {Bv[0], Bv[1], Bv[2], Bv[3]};
    *(floatx4*)(Aarr + sidx) = oA;
    *(floatx4*)(Barr + sidx) = oB;
}

__global__ __launch_bounds__(256) void scan2_kernel(const float* __restrict__ Aarr,
                                                    const float* __restrict__ Barr,
                                                    float* __restrict__ hin) {
    const int id = blockIdx.x * 256 + threadIdx.x;  // 0..2047
    const int b = id >> 8, d0 = (id & 255) * 4;
    float h[4] = {0.f, 0.f, 0.f, 0.f};
    for (int c = 0; c < NCHUNK; c++) {
        size_t idx = ((size_t)b * NCHUNK + c) * D_ + d0;
        floatx4 oh = {h[0], h[1], h[2], h[3]};
        *(floatx4*)(hin + idx) = oh;
        floatx4 a = *(const floatx4*)(Aarr + idx);
        floatx4 bb = *(const floatx4*)(Barr + idx);
#pragma unroll
        for (int j = 0; j < 4; j++) h[j] = a[j] * h[j] + bb[j];
    }
}

__global__ __launch_bounds__(256) void scan3_kernel(const u16* __restrict__ f_buf,
                                                    const u16* __restrict__ v_buf,
                                                    u16* g_io,
                                                    const float* __restrict__ hin) {
    const int wid = blockIdx.x * 4 + (threadIdx.x >> 6);  // 0..2047
    const int lane = threadIdx.x & 63;
    const int b = wid >> 8;
    const int rem = wid & 255;
    const int c = rem >> 2;
    const int d0 = (rem & 3) * 256 + lane * 4;
    size_t base = ((size_t)b * L_ + c * CLEN) * D_ + d0;
    floatx4 hv = *(const floatx4*)(hin + ((size_t)b * NCHUNK + c) * D_ + d0);
    float h[4] = {hv[0], hv[1], hv[2], hv[3]};
#pragma unroll 2
    for (int tt = 0; tt < CLEN; tt++) {
        size_t idx = base + (size_t)tt * D_;
        ushort4v f4 = *(const ushort4v*)(f_buf + idx);
        ushort4v v4 = *(const ushort4v*)(v_buf + idx);
        ushort4v g4 = *(const ushort4v*)(g_io + idx);
        ushort4v o;
#pragma unroll
        for (int j = 0; j < 4; j++) {
            float fv = bf2f(f4[j]);
            float vv = bf2f(v4[j]);
            float gv = bf2f(g4[j]);
            h[j] = fv * h[j] + (1.f - fv) * vv;
            o[j] = f2bf(gv * h[j]);
        }
        *(ushort4v*)(g_io + idx) = o;
    }
}

extern "C" void kernel_launch(void* const* d_in, const int* in_sizes, int n_in,
                              void* d_out, int out_size, void* d_ws, size_t ws_size,
                              hipStream_t stream) {
    const float* x     = (const float*)d_in[0];  // [8,4096,1024] fp32
    const float* w_in  = (const float*)d_in[1];  // [3072,1024]  fp32
    const float* w_out = (const float*)d_in[2];  // [1024,1024]  fp32
    const float* scale = (const float*)d_in[3];  // [1024]       fp32
    float* out = (float*)d_out;                  // [8,4096,1024] fp32 (128 MiB)

    // d_out doubles as scratch before the final GEMM: f and v bf16 planes.
    u16* f_buf = (u16*)d_out;                        // 64 MiB
    u16* v_buf = (u16*)d_out + (size_t)M_ * D_;      // 64 MiB

    // Workspace (~142 MiB): xn(64) + g(64) + w_in_bf(6) + w_out_bf(2) + scan(6)
    char* ws = (char*)d_ws;
    const size_t PLANE = (size_t)M_ * D_ * sizeof(u16);  // 64 MiB
    u16* xn    = (u16*)ws;
    u16* g_buf = (u16*)(ws + PLANE);
    u16* w_in_bf  = (u16*)(ws + 2 * PLANE);
    u16* w_out_bf = w_in_bf + WIN_ELEMS;
    float* Aarr = (float*)(ws + 2 * PLANE + (WIN_ELEMS + WOUT_ELEMS) * sizeof(u16));
    float* Barr = Aarr + (size_t)B_ * NCHUNK * D_;
    float* hin  = Barr + (size_t)B_ * NCHUNK * D_;

    prep_kernel<<<M_ + PREPW_BLOCKS, 256, 0, stream>>>(x, scale, xn, w_in, w_out,
                                                       w_in_bf, w_out_bf);
    gemm1_kernel<<<dim3(3 * D_ / 256, M_ / 256), 512, 0, stream>>>(
        xn, w_in_bf, g_buf, v_buf, f_buf);
    scan1_kernel<<<512, 256, 0, stream>>>(f_buf, v_buf, Aarr, Barr);
    scan2_kernel<<<8, 256, 0, stream>>>(Aarr, Barr, hin);
    scan3_kernel<<<512, 256, 0, stream>>>(f_buf, v_buf, g_buf, hin);
    gemm2_kernel<<<dim3(D_ / 256, M_ / 256), 512, 0, stream>>>(g_buf, w_out_bf, x, out);
}